// Round 16
// baseline (256.220 us; speedup 1.0000x reference)
//
#include <hip/hip_runtime.h>

#define B_ 1024
#define N_ 24
#define CI_ 2
#define CO_ 2
#define E_ 256
#define H_ 4
#define DH_ 64
#define M_ (B_ * CI_ * N_)  // 49152 flattened rows, order m = (b*2+i)*24 + n

typedef __bf16 v8bf __attribute__((ext_vector_type(8)));
typedef float v4f __attribute__((ext_vector_type(4)));

union Frag {
    uint4 u;
    v8bf v;
};

union Pack4 {
    ushort4 u;
    __bf16 h[4];
};

__device__ __forceinline__ v4f mfma16(v8bf a, v8bf b, v4f c) {
    return __builtin_amdgcn_mfma_f32_16x16x32_bf16(a, b, c, 0, 0, 0);
}

// load 8 consecutive f32 and round to 8 bf16
__device__ __forceinline__ v8bf cvt8(const float* __restrict__ p) {
    float4 a = *(const float4*)p;
    float4 b = *(const float4*)(p + 4);
    v8bf r;
    r[0] = (__bf16)a.x; r[1] = (__bf16)a.y; r[2] = (__bf16)a.z; r[3] = (__bf16)a.w;
    r[4] = (__bf16)b.x; r[5] = (__bf16)b.y; r[6] = (__bf16)b.z; r[7] = (__bf16)b.w;
    return r;
}

// async global->LDS DMA, 16B per lane (dst is wave-uniform base + lane*16)
__device__ __forceinline__ void gload16(const __bf16* g, __bf16* l) {
    __builtin_amdgcn_global_load_lds(
        (const __attribute__((address_space(1))) unsigned int*)g,
        (__attribute__((address_space(3))) unsigned int*)l, 16, 0, 0);
}

// ---------------------------------------------------------------------------
// Kernel PREP (merged ktrans + kfeatb): blocks [0,1584) transpose the 96
// kernel mats + Wq/Wk/Wv to bf16; blocks [1584,7728) downcast feat -> featb
// with the (b,i,n) row permutation.
// ---------------------------------------------------------------------------
__global__ __launch_bounds__(256) void kprep(
    const float* __restrict__ kern, const float* __restrict__ wq,
    const float* __restrict__ wk, const float* __restrict__ wv,
    const float* __restrict__ feat,
    __bf16* __restrict__ wt, __bf16* __restrict__ kt,
    __bf16* __restrict__ featb) {
    const int blk = blockIdx.x;
    const int tid = threadIdx.x;
    if (blk < 1584) {
        // ---- transpose path ----
        __shared__ __bf16 t[64][65];
        const int mat = blk >> 4, tile = blk & 15;
        const int r0 = (tile >> 2) * 64, c0 = (tile & 3) * 64;
        const float* src;
        __bf16* dst;
        if (mat < 96) {
            src = kern + (size_t)mat * 65536;
            dst = kt + (size_t)mat * 65536;
        } else {
            int p = mat - 96;
            src = (p == 0) ? wq : (p == 1) ? wk : wv;
            dst = wt + (size_t)p * 65536;
        }
#pragma unroll
        for (int k = 0; k < 16; ++k) {
            int idx = k * 256 + tid;
            int e = idx >> 6, f = idx & 63;
            t[f][e] = (__bf16)src[(size_t)(r0 + e) * 256 + c0 + f];
        }
        __syncthreads();
#pragma unroll
        for (int k = 0; k < 16; ++k) {
            int idx = k * 256 + tid;
            int f = idx >> 6, e = idx & 63;
            dst[(size_t)(c0 + f) * 256 + r0 + e] = t[f][e];
        }
    } else {
        // ---- feat downcast/permute path ----
        const int t = (blk - 1584) * 256 + tid;
        const int m = t >> 5;           // 32 threads per 256-elem row
        const int e0 = (t & 31) * 8;
        const int b = m / 48, r2 = m % 48;
        const int i = r2 / 24, n = r2 % 24;
        const float* src = feat + (((size_t)(b * 24 + n) * 2 + i) * 256 + e0);
        v8bf v = cvt8(src);
        *(v8bf*)(featb + ((size_t)m << 8) + e0) = v;
    }
}

// ---------------------------------------------------------------------------
// Kernel QKV2: C[49152 x 768] = featb . [Wq|Wk|Wv]^T as a tiled GEMM.
// XOR slot swizzle + XCD-aware bijective 1D grid (id%8 == by&7). FROZEN.
// ---------------------------------------------------------------------------
__global__ __launch_bounds__(512) void kqkv2(
    const __bf16* __restrict__ featb, const __bf16* __restrict__ wt,
    const float* __restrict__ bq, const float* __restrict__ bk,
    const float* __restrict__ bv,
    __bf16* __restrict__ gQ, __bf16* __restrict__ gK, __bf16* __restrict__ gVT) {
    __shared__ __bf16 sF[128 * 64];  // 16 KB feat tile [row][64k] (swizzled slots)
    __shared__ __bf16 sW[128 * 64];  // 16 KB weight tile [f][64k]

    const int id = blockIdx.x;       // 0..2303
    const int g = id >> 3, r8 = id & 7;
    const int cb = g % 6;            // col-block: 2 per matrix
    const int by = (g / 6) * 8 + r8; // 0..383
    const int m0 = by * 128;
    const int m3 = cb >> 1;           // matrix: 0=Q 1=K 2=V
    const int f0 = (cb & 1) * 128;    // f-half
    const bool vpath = (cb >= 4);
    const int tid = threadIdx.x;
    const int w = tid >> 6, lane = tid & 63;
    const int quad = lane >> 4, l16 = lane & 15;
    const int wr = w >> 1, wc = w & 1;  // wave tile: rows wr*32, cols wc*64

    const int srow = lane >> 3;              // 0..7 row within 8-row chunk
    const int sslot = (lane & 7) ^ srow;     // pre-swizzled global 16B slot
    const int rkey = l16 & 7;                // reader swizzle key (row&7)

    const v4f zf = {0.f, 0.f, 0.f, 0.f};
    v4f acc[2][4];
#pragma unroll
    for (int ri = 0; ri < 2; ++ri)
#pragma unroll
        for (int ci = 0; ci < 4; ++ci) acc[ri][ci] = zf;

#pragma unroll
    for (int s = 0; s < 4; ++s) {
        const int kb = s * 64;
#pragma unroll
        for (int j = 0; j < 2; ++j) {
            const int r = w * 16 + j * 8 + srow;
            gload16(featb + (((size_t)(m0 + r)) << 8) + kb + sslot * 8,
                    sF + (w * 16 + j * 8) * 64);
            gload16(wt + (((size_t)(m3 * 256 + f0 + r)) << 8) + kb + sslot * 8,
                    sW + (w * 16 + j * 8) * 64);
        }
        __syncthreads();

        const __bf16* As = vpath ? (const __bf16*)sF : (const __bf16*)sW;
        const __bf16* Bs = vpath ? (const __bf16*)sW : (const __bf16*)sF;
#pragma unroll
        for (int kk2 = 0; kk2 < 2; ++kk2) {
            const int sl = ((quad + 4 * kk2) ^ rkey) * 8;
            Frag fa[2], fb[4];
#pragma unroll
            for (int ri = 0; ri < 2; ++ri)
                fa[ri].u = *(const uint4*)(As + (wr * 32 + ri * 16 + l16) * 64 + sl);
#pragma unroll
            for (int ci = 0; ci < 4; ++ci)
                fb[ci].u = *(const uint4*)(Bs + (wc * 64 + ci * 16 + l16) * 64 + sl);
#pragma unroll
            for (int ri = 0; ri < 2; ++ri)
#pragma unroll
                for (int ci = 0; ci < 4; ++ci)
                    acc[ri][ci] = mfma16(fa[ri].v, fb[ci].v, acc[ri][ci]);
        }
        __syncthreads();
    }

    if (!vpath) {
        __bf16* dst = (cb < 2) ? gQ : gK;
        const float* bvec = (cb < 2) ? bq : bk;
#pragma unroll
        for (int ri = 0; ri < 2; ++ri) {
            const int fg0 = f0 + wr * 32 + ri * 16 + quad * 4;
            const float4 b4 = *(const float4*)(bvec + fg0);
#pragma unroll
            for (int ci = 0; ci < 4; ++ci) {
                const int mg = m0 + wc * 64 + ci * 16 + l16;
                Pack4 p;
                p.h[0] = (__bf16)(acc[ri][ci][0] + b4.x);
                p.h[1] = (__bf16)(acc[ri][ci][1] + b4.y);
                p.h[2] = (__bf16)(acc[ri][ci][2] + b4.z);
                p.h[3] = (__bf16)(acc[ri][ci][3] + b4.w);
                *(ushort4*)(dst + (((size_t)mg) << 8) + fg0) = p.u;
            }
        }
    } else {
#pragma unroll
        for (int ri = 0; ri < 2; ++ri) {
            const int mg0 = m0 + wr * 32 + ri * 16 + quad * 4;
            const int bs = mg0 / 24, n0 = mg0 % 24;
#pragma unroll
            for (int ci = 0; ci < 4; ++ci) {
                const int fg = f0 + wc * 64 + ci * 16 + l16;
                const float bvf = bv[fg];
                Pack4 p;
                p.h[0] = (__bf16)(acc[ri][ci][0] + bvf);
                p.h[1] = (__bf16)(acc[ri][ci][1] + bvf);
                p.h[2] = (__bf16)(acc[ri][ci][2] + bvf);
                p.h[3] = (__bf16)(acc[ri][ci][3] + bvf);
                *(ushort4*)(gVT + ((size_t)bs * 256 + fg) * 24 + n0) = p.u;
            }
        }
    }
}

// ---------------------------------------------------------------------------
// Kernel A2: scores + softmax + PV with swapped PV operands (packed ctx
// stores). Round-6 version — FROZEN.
// ---------------------------------------------------------------------------
__global__ __launch_bounds__(256) void kattn2(
    const __bf16* __restrict__ gQ, const __bf16* __restrict__ gK,
    const __bf16* __restrict__ gVT, __bf16* __restrict__ ctx) {
    __shared__ __bf16 sP[H_][N_][56];  // 10.5 KB, wave-local rows

    const int bs = blockIdx.x;  // 0..2047
    const int tid = threadIdx.x;
    const int h = tid >> 6, lane = tid & 63;
    const int quad = lane >> 4, l16 = lane & 15;

    const uint4 zero4 = make_uint4(0u, 0u, 0u, 0u);
    const v4f zf = {0.f, 0.f, 0.f, 0.f};

    // ---- scores = Q K^T / 8 ----
    v4f sc[2][2];
#pragma unroll
    for (int mt = 0; mt < 2; ++mt)
#pragma unroll
        for (int nt = 0; nt < 2; ++nt) sc[mt][nt] = zf;

#pragma unroll
    for (int ks = 0; ks < 2; ++ks) {
        const int d0 = h * DH_ + ks * 32 + quad * 8;
        Frag a[2], bb[2];
#pragma unroll
        for (int mt = 0; mt < 2; ++mt) {
            const int qn = mt * 16 + l16;
            a[mt].u = (qn < N_) ? *(const uint4*)(gQ + (size_t)(bs * N_ + qn) * E_ + d0) : zero4;
        }
#pragma unroll
        for (int nt = 0; nt < 2; ++nt) {
            const int kn = nt * 16 + l16;
            bb[nt].u = (kn < N_) ? *(const uint4*)(gK + (size_t)(bs * N_ + kn) * E_ + d0) : zero4;
        }
#pragma unroll
        for (int mt = 0; mt < 2; ++mt)
#pragma unroll
            for (int nt = 0; nt < 2; ++nt)
                sc[mt][nt] = mfma16(a[mt].v, bb[nt].v, sc[mt][nt]);
    }

    // ---- softmax (rows in-register, 16-lane shuffles) ----
    const float scale = 0.125f;  // 1/sqrt(64)
#pragma unroll
    for (int mt = 0; mt < 2; ++mt) {
#pragma unroll
        for (int r = 0; r < 4; ++r) {
            const int qn = mt * 16 + quad * 4 + r;
            const float v0 = sc[mt][0][r] * scale;
            const float v1 = (l16 < 8) ? sc[mt][1][r] * scale : -3.0e38f;  // kn>=24 masked
            float mx = fmaxf(v0, v1);
#pragma unroll
            for (int m = 1; m < 16; m <<= 1) mx = fmaxf(mx, __shfl_xor(mx, m));
            const float e0 = __expf(v0 - mx);
            const float e1 = (l16 < 8) ? __expf(v1 - mx) : 0.f;
            float s = e0 + e1;
#pragma unroll
            for (int m = 1; m < 16; m <<= 1) s += __shfl_xor(s, m);
            const float inv = 1.f / s;
            if (qn < N_) {
                sP[h][qn][l16] = (__bf16)(e0 * inv);
                sP[h][qn][16 + l16] = (__bf16)(e1 * inv);
            }
        }
    }
    // no barrier: sP[h] is wave-local

    // ---- ctx = P @ V, computed transposed: D[f][qn] ----
    Frag pa[2], vb[4];
#pragma unroll
    for (int mt = 0; mt < 2; ++mt) {
        const int qn = mt * 16 + l16;
        pa[mt].u = (qn < N_) ? *(const uint4*)(&sP[h][qn][quad * 8]) : zero4;
    }
#pragma unroll
    for (int nt = 0; nt < 4; ++nt) {
        const int f = h * DH_ + nt * 16 + l16;
        // kn = quad*8 + j ; quad==3 -> kn in [24,32): P there is exactly 0
        vb[nt].u = (quad < 3) ? *(const uint4*)(gVT + (size_t)(bs * E_ + f) * N_ + quad * 8) : zero4;
    }
#pragma unroll
    for (int nt = 0; nt < 4; ++nt) {
#pragma unroll
        for (int mt = 0; mt < 2; ++mt) {
            v4f c0 = zf;
            c0 = mfma16(vb[nt].v, pa[mt].v, c0);  // A=V rows(f), B=P rows(qn)
            const int qn = mt * 16 + l16;
            if (qn < N_) {
                Pack4 p;
                p.h[0] = (__bf16)c0[0];
                p.h[1] = (__bf16)c0[1];
                p.h[2] = (__bf16)c0[2];
                p.h[3] = (__bf16)c0[3];
                *(ushort4*)(ctx + (((size_t)(bs * N_ + qn)) << 8) + h * DH_ + nt * 16 + quad * 4) = p.u;
            }
        }
    }
}

// ---------------------------------------------------------------------------
// Kernel P2: tiled GEMM for pkq + ctx-scale + bias + residual + LayerNorm.
// EXACT round-8/10 version (61-63 us, 249.7 total — session best). FROZEN:
// K=64 (r6), dbuf (r7), 32-row split (r9), NT-hints (r12), bf16-residual
// (r14) all regressed. Latency/structure-bound (vmcnt-drain barrier + 3
// blocks/CU grid limit), NOT traffic-bound (r14: -18MB FETCH -> +27% time).
// ---------------------------------------------------------------------------
__global__ __launch_bounds__(256) void kpkln2(
    const float* __restrict__ feat, const __bf16* __restrict__ featb,
    const __bf16* __restrict__ kt, const __bf16* __restrict__ ctx,
    const float* __restrict__ bias, const float* __restrict__ gamma,
    const float* __restrict__ beta, float* __restrict__ out) {
    __shared__ __bf16 sA[256 * 32];  // kt slice [f][32e], 16 KB
    __shared__ __bf16 sB[64 * 32];   // featb slice [b][32e], 4 KB

    const int id = blockIdx.x;
    const int n = id % 24;
    const int t2 = id / 24;   // 0..31
    const int o = t2 >> 4, bt = t2 & 15;
    const int tid = threadIdx.x;
    const int w = tid >> 6, lane = tid & 63;
    const int quad = lane >> 4, l16 = lane & 15;
    const int b0 = bt * 64;
    const int brow = b0 + w * 16 + l16;  // this lane's b row (C^T col)

    const v4f zf = {0.f, 0.f, 0.f, 0.f};
    float accf[16][4];
#pragma unroll
    for (int fi = 0; fi < 16; ++fi)
#pragma unroll
        for (int r = 0; r < 4; ++r) accf[fi][r] = 0.f;

#pragma unroll
    for (int i = 0; i < CI_; ++i) {
        const __bf16* Am = kt + ((size_t)((o * CI_ + i) * N_ + n)) * 65536;
        v4f g[16];
#pragma unroll
        for (int fi = 0; fi < 16; ++fi) g[fi] = zf;

#pragma unroll
        for (int ks = 0; ks < 8; ++ks) {
            const int kb = ks * 32;
            // stage kt slice: 16 KB = 16 wave-segments of 1 KB
#pragma unroll
            for (int j = 0; j < 4; ++j) {
                const int s = w * 4 + j;              // 0..15
                const int row = s * 16 + (lane >> 2);  // f row 0..255
                gload16(Am + (size_t)row * 256 + kb + (lane & 3) * 8,
                        sA + s * 512);
            }
            // stage featb slice: 4 KB = 4 wave-segments of 1 KB
            {
                const int row = w * 16 + (lane >> 2);  // b row 0..63
                const size_t m = ((size_t)(b0 + row) * 2 + i) * 24 + n;
                gload16(featb + (m << 8) + kb + (lane & 3) * 8,
                        sB + w * 512);
            }
            __syncthreads();  // drain DMA, make tiles visible

            Frag bfrag;
            bfrag.u = *(const uint4*)(sB + (w * 16 + l16) * 32 + quad * 8);
#pragma unroll
            for (int fi = 0; fi < 16; ++fi) {
                Frag afrag;
                afrag.u = *(const uint4*)(sA + (fi * 16 + l16) * 32 + quad * 8);
                g[fi] = mfma16(afrag.v, bfrag.v, g[fi]);
            }
            __syncthreads();  // protect LDS before next stage
        }

        // scale by ctx (packed ushort4: 4 consecutive f per lane) and accumulate
        const __bf16* cr = ctx + (((size_t)((brow * 2 + i) * 24 + n)) << 8) + quad * 4;
#pragma unroll
        for (int fi = 0; fi < 16; ++fi) {
            Pack4 p;
            p.u = *(const ushort4*)(cr + fi * 16);
#pragma unroll
            for (int r = 0; r < 4; ++r)
                accf[fi][r] += (float)p.h[r] * g[fi][r];
        }
    }

    // epilogue: +bias +residual, LayerNorm over f (256), store f32
    const float bias_no = bias[n * CO_ + o];
    const float* resid = feat + (((size_t)((brow * 24 + n) * 2 + o)) << 8) + quad * 4;
    float s = 0.f;
#pragma unroll
    for (int fi = 0; fi < 16; ++fi) {
        const float4 rv = *(const float4*)(resid + fi * 16);
        accf[fi][0] += bias_no + rv.x;
        accf[fi][1] += bias_no + rv.y;
        accf[fi][2] += bias_no + rv.z;
        accf[fi][3] += bias_no + rv.w;
#pragma unroll
        for (int r = 0; r < 4; ++r) s += accf[fi][r];
    }
    // cross-quad reduce (lane bits 4,5)
    s += __shfl_xor(s, 16);
    s += __shfl_xor(s, 32);
    const float mean = s * (1.f / 256.f);
    float s2 = 0.f;
#pragma unroll
    for (int fi = 0; fi < 16; ++fi)
#pragma unroll
        for (int r = 0; r < 4; ++r) {
            const float d = accf[fi][r] - mean;
            s2 += d * d;
        }
    s2 += __shfl_xor(s2, 16);
    s2 += __shfl_xor(s2, 32);
    const float rstd = rsqrtf(s2 * (1.f / 256.f) + 1e-12f);

    float* op = out + (((size_t)((brow * 24 + n) * 2 + o)) << 8) + quad * 4;
#pragma unroll
    for (int fi = 0; fi < 16; ++fi) {
        const int f = fi * 16 + quad * 4;
        const float4 gm = *(const float4*)(gamma + f);
        const float4 bt4 = *(const float4*)(beta + f);
        float4 ov;
        ov.x = (accf[fi][0] - mean) * rstd * gm.x + bt4.x;
        ov.y = (accf[fi][1] - mean) * rstd * gm.y + bt4.y;
        ov.z = (accf[fi][2] - mean) * rstd * gm.z + bt4.z;
        ov.w = (accf[fi][3] - mean) * rstd * gm.w + bt4.w;
        *(float4*)(op + fi * 16) = ov;
    }
}

// ---------------------------------------------------------------------------
extern "C" void kernel_launch(void* const* d_in, const int* in_sizes, int n_in,
                              void* d_out, int out_size, void* d_ws, size_t ws_size,
                              hipStream_t stream) {
    const float* feat = (const float*)d_in[0];
    const float* kern = (const float*)d_in[1];
    const float* bias = (const float*)d_in[2];
    const float* wq = (const float*)d_in[3];
    const float* bq = (const float*)d_in[4];
    const float* wk = (const float*)d_in[5];
    const float* bk = (const float*)d_in[6];
    const float* wv = (const float*)d_in[7];
    const float* bv = (const float*)d_in[8];
    const float* gamma = (const float*)d_in[9];
    const float* beta = (const float*)d_in[10];

    __bf16* ws = (__bf16*)d_ws;
    __bf16* wt = ws;                              // 3 * 65536
    __bf16* kt = wt + (size_t)3 * 65536;          // 96 * 65536
    __bf16* ctx = kt + (size_t)96 * 65536;        // [2048][24][256]
    __bf16* gQ = ctx + (size_t)2048 * 24 * 256;   // [49152][256]
    __bf16* gK = gQ + (size_t)M_ * 256;           // [49152][256]
    __bf16* gVT = gK + (size_t)M_ * 256;          // [2048][256][24]
    __bf16* featb = gVT + (size_t)2048 * 256 * 24;  // [49152][256]
    float* out = (float*)d_out;

    hipLaunchKernelGGL(kprep, dim3(1584 + 6144), dim3(256), 0, stream,
                       kern, wq, wk, wv, feat, wt, kt, featb);
    hipLaunchKernelGGL(kqkv2, dim3(6 * 384), dim3(512), 0, stream,
                       featb, wt, bq, bk, bv, gQ, gK, gVT);
    hipLaunchKernelGGL(kattn2, dim3(B_ * CI_), dim3(256), 0, stream,
                       gQ, gK, gVT, ctx);
    hipLaunchKernelGGL(kpkln2, dim3(24 * 32), dim3(256), 0, stream,
                       feat, featb, kt, ctx, bias, gamma, beta, out);
}

// Round 18
// 249.591 us; speedup vs baseline: 1.0266x; 1.0266x over previous
//
#include <hip/hip_runtime.h>

#define B_ 1024
#define N_ 24
#define CI_ 2
#define CO_ 2
#define E_ 256
#define H_ 4
#define DH_ 64
#define M_ (B_ * CI_ * N_)  // 49152 flattened rows, order m = (b*2+i)*24 + n

typedef __bf16 v8bf __attribute__((ext_vector_type(8)));
typedef float v4f __attribute__((ext_vector_type(4)));

union Frag {
    uint4 u;
    v8bf v;
};

union Pack4 {
    ushort4 u;
    __bf16 h[4];
};

__device__ __forceinline__ v4f mfma16(v8bf a, v8bf b, v4f c) {
    return __builtin_amdgcn_mfma_f32_16x16x32_bf16(a, b, c, 0, 0, 0);
}

// load 8 consecutive f32 and round to 8 bf16
__device__ __forceinline__ v8bf cvt8(const float* __restrict__ p) {
    float4 a = *(const float4*)p;
    float4 b = *(const float4*)(p + 4);
    v8bf r;
    r[0] = (__bf16)a.x; r[1] = (__bf16)a.y; r[2] = (__bf16)a.z; r[3] = (__bf16)a.w;
    r[4] = (__bf16)b.x; r[5] = (__bf16)b.y; r[6] = (__bf16)b.z; r[7] = (__bf16)b.w;
    return r;
}

// async global->LDS DMA, 16B per lane (dst is wave-uniform base + lane*16)
__device__ __forceinline__ void gload16(const __bf16* g, __bf16* l) {
    __builtin_amdgcn_global_load_lds(
        (const __attribute__((address_space(1))) unsigned int*)g,
        (__attribute__((address_space(3))) unsigned int*)l, 16, 0, 0);
}

// ---------------------------------------------------------------------------
// Kernel PREP (merged ktrans + kfeatb): blocks [0,1584) transpose the 96
// kernel mats + Wq/Wk/Wv to bf16; blocks [1584,7728) downcast feat -> featb
// with the (b,i,n) row permutation.
// NOTE (r17): the scores-associativity trick (G = Wq.Wk^T) is INVALID for
// multi-head attention — per-head scores need per-head G_h = Wq_h.Wk_h^T
// with a full-256 trailing contraction (4x work). Reverted.
// ---------------------------------------------------------------------------
__global__ __launch_bounds__(256) void kprep(
    const float* __restrict__ kern, const float* __restrict__ wq,
    const float* __restrict__ wk, const float* __restrict__ wv,
    const float* __restrict__ feat,
    __bf16* __restrict__ wt, __bf16* __restrict__ kt,
    __bf16* __restrict__ featb) {
    const int blk = blockIdx.x;
    const int tid = threadIdx.x;
    if (blk < 1584) {
        // ---- transpose path ----
        __shared__ __bf16 t[64][65];
        const int mat = blk >> 4, tile = blk & 15;
        const int r0 = (tile >> 2) * 64, c0 = (tile & 3) * 64;
        const float* src;
        __bf16* dst;
        if (mat < 96) {
            src = kern + (size_t)mat * 65536;
            dst = kt + (size_t)mat * 65536;
        } else {
            int p = mat - 96;
            src = (p == 0) ? wq : (p == 1) ? wk : wv;
            dst = wt + (size_t)p * 65536;
        }
#pragma unroll
        for (int k = 0; k < 16; ++k) {
            int idx = k * 256 + tid;
            int e = idx >> 6, f = idx & 63;
            t[f][e] = (__bf16)src[(size_t)(r0 + e) * 256 + c0 + f];
        }
        __syncthreads();
#pragma unroll
        for (int k = 0; k < 16; ++k) {
            int idx = k * 256 + tid;
            int f = idx >> 6, e = idx & 63;
            dst[(size_t)(c0 + f) * 256 + r0 + e] = t[f][e];
        }
    } else {
        // ---- feat downcast/permute path ----
        const int t = (blk - 1584) * 256 + tid;
        const int m = t >> 5;           // 32 threads per 256-elem row
        const int e0 = (t & 31) * 8;
        const int b = m / 48, r2 = m % 48;
        const int i = r2 / 24, n = r2 % 24;
        const float* src = feat + (((size_t)(b * 24 + n) * 2 + i) * 256 + e0);
        v8bf v = cvt8(src);
        *(v8bf*)(featb + ((size_t)m << 8) + e0) = v;
    }
}

// ---------------------------------------------------------------------------
// Kernel QKV2: C[49152 x 768] = featb . [Wq|Wk|Wv]^T as a tiled GEMM.
// XOR slot swizzle + XCD-aware bijective 1D grid (id%8 == by&7). FROZEN.
// ---------------------------------------------------------------------------
__global__ __launch_bounds__(512) void kqkv2(
    const __bf16* __restrict__ featb, const __bf16* __restrict__ wt,
    const float* __restrict__ bq, const float* __restrict__ bk,
    const float* __restrict__ bv,
    __bf16* __restrict__ gQ, __bf16* __restrict__ gK, __bf16* __restrict__ gVT) {
    __shared__ __bf16 sF[128 * 64];  // 16 KB feat tile [row][64k] (swizzled slots)
    __shared__ __bf16 sW[128 * 64];  // 16 KB weight tile [f][64k]

    const int id = blockIdx.x;       // 0..2303
    const int g = id >> 3, r8 = id & 7;
    const int cb = g % 6;            // col-block: 2 per matrix
    const int by = (g / 6) * 8 + r8; // 0..383
    const int m0 = by * 128;
    const int m3 = cb >> 1;           // matrix: 0=Q 1=K 2=V
    const int f0 = (cb & 1) * 128;    // f-half
    const bool vpath = (cb >= 4);
    const int tid = threadIdx.x;
    const int w = tid >> 6, lane = tid & 63;
    const int quad = lane >> 4, l16 = lane & 15;
    const int wr = w >> 1, wc = w & 1;  // wave tile: rows wr*32, cols wc*64

    const int srow = lane >> 3;              // 0..7 row within 8-row chunk
    const int sslot = (lane & 7) ^ srow;     // pre-swizzled global 16B slot
    const int rkey = l16 & 7;                // reader swizzle key (row&7)

    const v4f zf = {0.f, 0.f, 0.f, 0.f};
    v4f acc[2][4];
#pragma unroll
    for (int ri = 0; ri < 2; ++ri)
#pragma unroll
        for (int ci = 0; ci < 4; ++ci) acc[ri][ci] = zf;

#pragma unroll
    for (int s = 0; s < 4; ++s) {
        const int kb = s * 64;
#pragma unroll
        for (int j = 0; j < 2; ++j) {
            const int r = w * 16 + j * 8 + srow;
            gload16(featb + (((size_t)(m0 + r)) << 8) + kb + sslot * 8,
                    sF + (w * 16 + j * 8) * 64);
            gload16(wt + (((size_t)(m3 * 256 + f0 + r)) << 8) + kb + sslot * 8,
                    sW + (w * 16 + j * 8) * 64);
        }
        __syncthreads();

        const __bf16* As = vpath ? (const __bf16*)sF : (const __bf16*)sW;
        const __bf16* Bs = vpath ? (const __bf16*)sW : (const __bf16*)sF;
#pragma unroll
        for (int kk2 = 0; kk2 < 2; ++kk2) {
            const int sl = ((quad + 4 * kk2) ^ rkey) * 8;
            Frag fa[2], fb[4];
#pragma unroll
            for (int ri = 0; ri < 2; ++ri)
                fa[ri].u = *(const uint4*)(As + (wr * 32 + ri * 16 + l16) * 64 + sl);
#pragma unroll
            for (int ci = 0; ci < 4; ++ci)
                fb[ci].u = *(const uint4*)(Bs + (wc * 64 + ci * 16 + l16) * 64 + sl);
#pragma unroll
            for (int ri = 0; ri < 2; ++ri)
#pragma unroll
                for (int ci = 0; ci < 4; ++ci)
                    acc[ri][ci] = mfma16(fa[ri].v, fb[ci].v, acc[ri][ci]);
        }
        __syncthreads();
    }

    if (!vpath) {
        __bf16* dst = (cb < 2) ? gQ : gK;
        const float* bvec = (cb < 2) ? bq : bk;
#pragma unroll
        for (int ri = 0; ri < 2; ++ri) {
            const int fg0 = f0 + wr * 32 + ri * 16 + quad * 4;
            const float4 b4 = *(const float4*)(bvec + fg0);
#pragma unroll
            for (int ci = 0; ci < 4; ++ci) {
                const int mg = m0 + wc * 64 + ci * 16 + l16;
                Pack4 p;
                p.h[0] = (__bf16)(acc[ri][ci][0] + b4.x);
                p.h[1] = (__bf16)(acc[ri][ci][1] + b4.y);
                p.h[2] = (__bf16)(acc[ri][ci][2] + b4.z);
                p.h[3] = (__bf16)(acc[ri][ci][3] + b4.w);
                *(ushort4*)(dst + (((size_t)mg) << 8) + fg0) = p.u;
            }
        }
    } else {
#pragma unroll
        for (int ri = 0; ri < 2; ++ri) {
            const int mg0 = m0 + wr * 32 + ri * 16 + quad * 4;
            const int bs = mg0 / 24, n0 = mg0 % 24;
#pragma unroll
            for (int ci = 0; ci < 4; ++ci) {
                const int fg = f0 + wc * 64 + ci * 16 + l16;
                const float bvf = bv[fg];
                Pack4 p;
                p.h[0] = (__bf16)(acc[ri][ci][0] + bvf);
                p.h[1] = (__bf16)(acc[ri][ci][1] + bvf);
                p.h[2] = (__bf16)(acc[ri][ci][2] + bvf);
                p.h[3] = (__bf16)(acc[ri][ci][3] + bvf);
                *(ushort4*)(gVT + ((size_t)bs * 256 + fg) * 24 + n0) = p.u;
            }
        }
    }
}

// ---------------------------------------------------------------------------
// Kernel A2: scores + softmax + PV with swapped PV operands (packed ctx
// stores). Round-6 version — FROZEN.
// ---------------------------------------------------------------------------
__global__ __launch_bounds__(256) void kattn2(
    const __bf16* __restrict__ gQ, const __bf16* __restrict__ gK,
    const __bf16* __restrict__ gVT, __bf16* __restrict__ ctx) {
    __shared__ __bf16 sP[H_][N_][56];  // 10.5 KB, wave-local rows

    const int bs = blockIdx.x;  // 0..2047
    const int tid = threadIdx.x;
    const int h = tid >> 6, lane = tid & 63;
    const int quad = lane >> 4, l16 = lane & 15;

    const uint4 zero4 = make_uint4(0u, 0u, 0u, 0u);
    const v4f zf = {0.f, 0.f, 0.f, 0.f};

    // ---- scores = Q K^T / 8 ----
    v4f sc[2][2];
#pragma unroll
    for (int mt = 0; mt < 2; ++mt)
#pragma unroll
        for (int nt = 0; nt < 2; ++nt) sc[mt][nt] = zf;

#pragma unroll
    for (int ks = 0; ks < 2; ++ks) {
        const int d0 = h * DH_ + ks * 32 + quad * 8;
        Frag a[2], bb[2];
#pragma unroll
        for (int mt = 0; mt < 2; ++mt) {
            const int qn = mt * 16 + l16;
            a[mt].u = (qn < N_) ? *(const uint4*)(gQ + (size_t)(bs * N_ + qn) * E_ + d0) : zero4;
        }
#pragma unroll
        for (int nt = 0; nt < 2; ++nt) {
            const int kn = nt * 16 + l16;
            bb[nt].u = (kn < N_) ? *(const uint4*)(gK + (size_t)(bs * N_ + kn) * E_ + d0) : zero4;
        }
#pragma unroll
        for (int mt = 0; mt < 2; ++mt)
#pragma unroll
            for (int nt = 0; nt < 2; ++nt)
                sc[mt][nt] = mfma16(a[mt].v, bb[nt].v, sc[mt][nt]);
    }

    // ---- softmax (rows in-register, 16-lane shuffles) ----
    const float scale = 0.125f;  // 1/sqrt(64)
#pragma unroll
    for (int mt = 0; mt < 2; ++mt) {
#pragma unroll
        for (int r = 0; r < 4; ++r) {
            const int qn = mt * 16 + quad * 4 + r;
            const float v0 = sc[mt][0][r] * scale;
            const float v1 = (l16 < 8) ? sc[mt][1][r] * scale : -3.0e38f;  // kn>=24 masked
            float mx = fmaxf(v0, v1);
#pragma unroll
            for (int m = 1; m < 16; m <<= 1) mx = fmaxf(mx, __shfl_xor(mx, m));
            const float e0 = __expf(v0 - mx);
            const float e1 = (l16 < 8) ? __expf(v1 - mx) : 0.f;
            float s = e0 + e1;
#pragma unroll
            for (int m = 1; m < 16; m <<= 1) s += __shfl_xor(s, m);
            const float inv = 1.f / s;
            if (qn < N_) {
                sP[h][qn][l16] = (__bf16)(e0 * inv);
                sP[h][qn][16 + l16] = (__bf16)(e1 * inv);
            }
        }
    }
    // no barrier: sP[h] is wave-local

    // ---- ctx = P @ V, computed transposed: D[f][qn] ----
    Frag pa[2], vb[4];
#pragma unroll
    for (int mt = 0; mt < 2; ++mt) {
        const int qn = mt * 16 + l16;
        pa[mt].u = (qn < N_) ? *(const uint4*)(&sP[h][qn][quad * 8]) : zero4;
    }
#pragma unroll
    for (int nt = 0; nt < 4; ++nt) {
        const int f = h * DH_ + nt * 16 + l16;
        // kn = quad*8 + j ; quad==3 -> kn in [24,32): P there is exactly 0
        vb[nt].u = (quad < 3) ? *(const uint4*)(gVT + (size_t)(bs * E_ + f) * N_ + quad * 8) : zero4;
    }
#pragma unroll
    for (int nt = 0; nt < 4; ++nt) {
#pragma unroll
        for (int mt = 0; mt < 2; ++mt) {
            v4f c0 = zf;
            c0 = mfma16(vb[nt].v, pa[mt].v, c0);  // A=V rows(f), B=P rows(qn)
            const int qn = mt * 16 + l16;
            if (qn < N_) {
                Pack4 p;
                p.h[0] = (__bf16)c0[0];
                p.h[1] = (__bf16)c0[1];
                p.h[2] = (__bf16)c0[2];
                p.h[3] = (__bf16)c0[3];
                *(ushort4*)(ctx + (((size_t)(bs * N_ + qn)) << 8) + h * DH_ + nt * 16 + quad * 4) = p.u;
            }
        }
    }
}

// ---------------------------------------------------------------------------
// Kernel P2: tiled GEMM for pkq + ctx-scale + bias + residual + LayerNorm.
// EXACT round-8/10 version (61-63 us, 249.7 total — session best). FROZEN.
// ---------------------------------------------------------------------------
__global__ __launch_bounds__(256) void kpkln2(
    const float* __restrict__ feat, const __bf16* __restrict__ featb,
    const __bf16* __restrict__ kt, const __bf16* __restrict__ ctx,
    const float* __restrict__ bias, const float* __restrict__ gamma,
    const float* __restrict__ beta, float* __restrict__ out) {
    __shared__ __bf16 sA[256 * 32];  // kt slice [f][32e], 16 KB
    __shared__ __bf16 sB[64 * 32];   // featb slice [b][32e], 4 KB

    const int id = blockIdx.x;
    const int n = id % 24;
    const int t2 = id / 24;   // 0..31
    const int o = t2 >> 4, bt = t2 & 15;
    const int tid = threadIdx.x;
    const int w = tid >> 6, lane = tid & 63;
    const int quad = lane >> 4, l16 = lane & 15;
    const int b0 = bt * 64;
    const int brow = b0 + w * 16 + l16;  // this lane's b row (C^T col)

    const v4f zf = {0.f, 0.f, 0.f, 0.f};
    float accf[16][4];
#pragma unroll
    for (int fi = 0; fi < 16; ++fi)
#pragma unroll
        for (int r = 0; r < 4; ++r) accf[fi][r] = 0.f;

#pragma unroll
    for (int i = 0; i < CI_; ++i) {
        const __bf16* Am = kt + ((size_t)((o * CI_ + i) * N_ + n)) * 65536;
        v4f g[16];
#pragma unroll
        for (int fi = 0; fi < 16; ++fi) g[fi] = zf;

#pragma unroll
        for (int ks = 0; ks < 8; ++ks) {
            const int kb = ks * 32;
            // stage kt slice: 16 KB = 16 wave-segments of 1 KB
#pragma unroll
            for (int j = 0; j < 4; ++j) {
                const int s = w * 4 + j;              // 0..15
                const int row = s * 16 + (lane >> 2);  // f row 0..255
                gload16(Am + (size_t)row * 256 + kb + (lane & 3) * 8,
                        sA + s * 512);
            }
            // stage featb slice: 4 KB = 4 wave-segments of 1 KB
            {
                const int row = w * 16 + (lane >> 2);  // b row 0..63
                const size_t m = ((size_t)(b0 + row) * 2 + i) * 24 + n;
                gload16(featb + (m << 8) + kb + (lane & 3) * 8,
                        sB + w * 512);
            }
            __syncthreads();  // drain DMA, make tiles visible

            Frag bfrag;
            bfrag.u = *(const uint4*)(sB + (w * 16 + l16) * 32 + quad * 8);
#pragma unroll
            for (int fi = 0; fi < 16; ++fi) {
                Frag afrag;
                afrag.u = *(const uint4*)(sA + (fi * 16 + l16) * 32 + quad * 8);
                g[fi] = mfma16(afrag.v, bfrag.v, g[fi]);
            }
            __syncthreads();  // protect LDS before next stage
        }

        // scale by ctx (packed ushort4: 4 consecutive f per lane) and accumulate
        const __bf16* cr = ctx + (((size_t)((brow * 2 + i) * 24 + n)) << 8) + quad * 4;
#pragma unroll
        for (int fi = 0; fi < 16; ++fi) {
            Pack4 p;
            p.u = *(const ushort4*)(cr + fi * 16);
#pragma unroll
            for (int r = 0; r < 4; ++r)
                accf[fi][r] += (float)p.h[r] * g[fi][r];
        }
    }

    // epilogue: +bias +residual, LayerNorm over f (256), store f32
    const float bias_no = bias[n * CO_ + o];
    const float* resid = feat + (((size_t)((brow * 24 + n) * 2 + o)) << 8) + quad * 4;
    float s = 0.f;
#pragma unroll
    for (int fi = 0; fi < 16; ++fi) {
        const float4 rv = *(const float4*)(resid + fi * 16);
        accf[fi][0] += bias_no + rv.x;
        accf[fi][1] += bias_no + rv.y;
        accf[fi][2] += bias_no + rv.z;
        accf[fi][3] += bias_no + rv.w;
#pragma unroll
        for (int r = 0; r < 4; ++r) s += accf[fi][r];
    }
    // cross-quad reduce (lane bits 4,5)
    s += __shfl_xor(s, 16);
    s += __shfl_xor(s, 32);
    const float mean = s * (1.f / 256.f);
    float s2 = 0.f;
#pragma unroll
    for (int fi = 0; fi < 16; ++fi)
#pragma unroll
        for (int r = 0; r < 4; ++r) {
            const float d = accf[fi][r] - mean;
            s2 += d * d;
        }
    s2 += __shfl_xor(s2, 16);
    s2 += __shfl_xor(s2, 32);
    const float rstd = rsqrtf(s2 * (1.f / 256.f) + 1e-12f);

    float* op = out + (((size_t)((brow * 24 + n) * 2 + o)) << 8) + quad * 4;
#pragma unroll
    for (int fi = 0; fi < 16; ++fi) {
        const int f = fi * 16 + quad * 4;
        const float4 gm = *(const float4*)(gamma + f);
        const float4 bt4 = *(const float4*)(beta + f);
        float4 ov;
        ov.x = (accf[fi][0] - mean) * rstd * gm.x + bt4.x;
        ov.y = (accf[fi][1] - mean) * rstd * gm.y + bt4.y;
        ov.z = (accf[fi][2] - mean) * rstd * gm.z + bt4.z;
        ov.w = (accf[fi][3] - mean) * rstd * gm.w + bt4.w;
        *(float4*)(op + fi * 16) = ov;
    }
}

// ---------------------------------------------------------------------------
extern "C" void kernel_launch(void* const* d_in, const int* in_sizes, int n_in,
                              void* d_out, int out_size, void* d_ws, size_t ws_size,
                              hipStream_t stream) {
    const float* feat = (const float*)d_in[0];
    const float* kern = (const float*)d_in[1];
    const float* bias = (const float*)d_in[2];
    const float* wq = (const float*)d_in[3];
    const float* bq = (const float*)d_in[4];
    const float* wk = (const float*)d_in[5];
    const float* bk = (const float*)d_in[6];
    const float* wv = (const float*)d_in[7];
    const float* bv = (const float*)d_in[8];
    const float* gamma = (const float*)d_in[9];
    const float* beta = (const float*)d_in[10];

    __bf16* ws = (__bf16*)d_ws;
    __bf16* wt = ws;                              // 3 * 65536
    __bf16* kt = wt + (size_t)3 * 65536;          // 96 * 65536
    __bf16* ctx = kt + (size_t)96 * 65536;        // [2048][24][256]
    __bf16* gQ = ctx + (size_t)2048 * 24 * 256;   // [49152][256]
    __bf16* gK = gQ + (size_t)M_ * 256;           // [49152][256]
    __bf16* gVT = gK + (size_t)M_ * 256;          // [2048][256][24]
    __bf16* featb = gVT + (size_t)2048 * 256 * 24;  // [49152][256]
    float* out = (float*)d_out;

    hipLaunchKernelGGL(kprep, dim3(1584 + 6144), dim3(256), 0, stream,
                       kern, wq, wk, wv, feat, wt, kt, featb);
    hipLaunchKernelGGL(kqkv2, dim3(6 * 384), dim3(512), 0, stream,
                       featb, wt, bq, bk, bv, gQ, gK, gVT);
    hipLaunchKernelGGL(kattn2, dim3(B_ * CI_), dim3(256), 0, stream,
                       gQ, gK, gVT, ctx);
    hipLaunchKernelGGL(kpkln2, dim3(24 * 32), dim3(256), 0, stream,
                       feat, featb, kt, ctx, bias, gamma, beta, out);
}